// Round 2
// baseline (521.264 us; speedup 1.0000x reference)
//
#include <hip/hip_runtime.h>
#include <math.h>

#define NN   128
#define PSTR 130          // pool stride (floats): even -> 8B-aligned rows; bank stride 2 (free)
#define NTH  512

__device__ __forceinline__ float sp_softplus(float x) { return log1pf(expf(x)); }
__device__ __forceinline__ float rdlane(float v, int l) {
    return __int_as_float(__builtin_amdgcn_readlane(__float_as_int(v), l));
}

__global__ void __launch_bounds__(NTH, 4)   // 4 waves/SIMD => 2 blocks/CU, caps VGPR at 128
ts_gcn_kernel(const float* __restrict__ edge_pred,
              const int*   __restrict__ adj,
              const float* __restrict__ d_init,
              const float* __restrict__ u_init,
              const float* __restrict__ x_noise,
              float* __restrict__ out)
{
    __shared__ __align__(16) float pool[NN * PSTR];  // 66560 B, reused 3x for staging
    __shared__ unsigned maskb[512];                  // output mask bits (diag excluded)
    __shared__ int s_cntM, s_cntN0;

    // post-staging aliases (first use strictly after last pool staging read)
    float* scrx = pool;            // [512]
    float* scry = pool + 512;      // [512]
    float* scrz = pool + 1024;     // [512]
    float* Xx   = pool + 1536;     // [128] (16B-aligned offset)
    float* Xy   = pool + 1664;     // [128]
    float* Xz   = pool + 1792;     // [128]
    float* u_s  = pool + 1920;     // [128]
    float* r_s  = pool + 2048;     // [128]

    const int b    = blockIdx.x;
    const int t    = threadIdx.x;
    const int lane = t & 63;
    const int i    = t & 127;      // owned row
    const int q    = t >> 7;       // column quarter
    const int jb   = q * 32;
    const int lsel = jb & 63;

    const float dini = d_init[0];
    if (t == 0) { s_cntM = 0; s_cntN0 = 0; }

    // ---------------- Pass A: stage adj, build mask bitmap ----------------
    const int4* adj4 = (const int4*)(adj + (size_t)b * 16384);
    #pragma unroll
    for (int k = 0; k < 8; ++k) {
        int e4 = t + k * 512;                 // int4 index
        int4 v = adj4[e4];
        int ii = e4 >> 5, jj = (e4 & 31) * 4;
        float* p = &pool[ii * PSTR + jj];
        p[0] = __int_as_float(v.x); p[1] = __int_as_float(v.y);
        p[2] = __int_as_float(v.z); p[3] = __int_as_float(v.w);
    }
    __syncthreads();
    unsigned mword = 0;
    #pragma unroll
    for (int k = 0; k < 32; ++k) {
        int j = jb + k;
        int a = __float_as_int(pool[i * PSTR + j]) | __float_as_int(pool[j * PSTR + i]);
        if (a != 0 && i != j) mword |= (1u << k);
    }
    maskb[i * 4 + q] = mword;
    int cm = __popc(mword);
    #pragma unroll
    for (int off = 32; off > 0; off >>= 1) cm += __shfl_xor(cm, off);
    if (lane == 0) atomicAdd(&s_cntM, cm);
    if (i == 0)   atomicAdd(&s_cntN0, __popc(mword));   // row 0 == col 0 by symmetry
    __syncthreads();

    // ---------------- Pass B: stage ep.ch0, compute D (registers) ----------------
    const float4* ep4 = (const float4*)(edge_pred + (size_t)b * 32768);
    #pragma unroll
    for (int k = 0; k < 16; ++k) {
        int e2 = t + k * 512;                 // element-pair index
        float4 v = ep4[e2];
        int ii = e2 >> 6, jj = (e2 & 63) * 2;
        *(float2*)&pool[ii * PSTR + jj] = make_float2(v.x, v.z);
    }
    __syncthreads();
    float Dreg[32];
    #pragma unroll
    for (int k = 0; k < 32; ++k) {
        int j = jb + k;
        float s = pool[i * PSTR + j] + pool[j * PSTR + i];
        Dreg[k] = ((mword >> k) & 1) ? sp_softplus(dini + s) : 0.f;
    }
    __syncthreads();

    // ---------------- Pass C: stage ep.ch1, compute W (registers) ----------------
    #pragma unroll
    for (int k = 0; k < 16; ++k) {
        int e2 = t + k * 512;
        float4 v = ep4[e2];
        int ii = e2 >> 6, jj = (e2 & 63) * 2;
        *(float2*)&pool[ii * PSTR + jj] = make_float2(v.y, v.w);
    }
    __syncthreads();
    float Wreg[32];
    #pragma unroll
    for (int k = 0; k < 32; ++k) {
        int j = jb + k;
        float s = pool[i * PSTR + j] + pool[j * PSTR + i];
        Wreg[k] = ((mword >> k) & 1) ? sp_softplus(dini + s) : 0.f;
    }
    __syncthreads();   // pool free: aliases live from here on

    // ---------------- Row sums of D^2 and grand mean ----------------
    float rp = 0.f;
    #pragma unroll
    for (int k = 0; k < 32; ++k) rp = fmaf(Dreg[k], Dreg[k], rp);
    scrx[t] = rp;
    __syncthreads();
    if (t < NN)
        r_s[t] = (scrx[t] + scrx[t + 128]) + (scrx[t + 256] + scrx[t + 384]);
    __syncthreads();

    float mt = r_s[lane] + r_s[lane + 64];
    #pragma unroll
    for (int off = 32; off > 0; off >>= 1) mt += __shfl_xor(mt, off);

    const float Nmol  = (float)(1 + s_cntN0);
    const float Minv  = 1.0f / (float)(128 + s_cntM);
    const float invN  = 1.0f / Nmol;
    const float cmean = mt * invN * invN;

    // ---------------- Gram matrix into registers ----------------
    const float ri = r_s[i];
    float Bg[32];
    #pragma unroll
    for (int k = 0; k < 32; ++k) {
        int j = jb + k;
        float dv = Dreg[k];
        float v  = -0.5f * (dv * dv - ri * invN - r_s[j] * invN + cmean);
        bool msk = (dv > 0.f) || (i == j);
        Bg[k] = msk ? v : 0.f;
    }

    // ---------------- Power iteration: 3 ranks x 10 steps ----------------
    const float* ub = u_init  + (size_t)b * 384;
    const float* xb = x_noise + (size_t)b * 384;

    #pragma unroll 1
    for (int kx = 0; kx < 3; ++kx) {
        if (t < NN) u_s[t] = ub[t * 3 + kx];
        __syncthreads();

        #pragma unroll 1
        for (int s = 0; s < 10; ++s) {
            float ulo = u_s[lane], uhi = u_s[lane + 64];
            float n2 = fmaf(ulo, ulo, uhi * uhi);
            #pragma unroll
            for (int off = 32; off > 0; off >>= 1) n2 += __shfl_xor(n2, off);
            float inv = 1.0f / fmaxf(sqrtf(n2), 0.001f);   // normalization folded post-matvec

            float usel = (q < 2) ? ulo : uhi;              // wave-uniform half select
            float a0 = 0.f, a1 = 0.f;
            #pragma unroll
            for (int k = 0; k < 16; ++k) {
                a0 = fmaf(Bg[k],      rdlane(usel, lsel + k),      a0);
                a1 = fmaf(Bg[k + 16], rdlane(usel, lsel + k + 16), a1);
            }
            scrx[t] = a0 + a1;
            __syncthreads();
            if (t < NN)
                u_s[t] = ((scrx[t] + scrx[t + 128]) + (scrx[t + 256] + scrx[t + 384])) * inv;
            __syncthreads();
        }

        float ulo = u_s[lane], uhi = u_s[lane + 64];
        float e2 = fmaf(ulo, ulo, uhi * uhi);
        #pragma unroll
        for (int off = 32; off > 0; off >>= 1) e2 += __shfl_xor(e2, off);
        float esc  = 1.0f / sqrtf(sqrtf(e2 + 0.01f));      // (eig_sq+0.01)^-0.25
        float ufi  = u_s[i] * esc;
        float uscl = ((q < 2) ? ulo : uhi) * esc;
        #pragma unroll
        for (int k = 0; k < 32; ++k)
            Bg[k] = fmaf(-ufi, rdlane(uscl, lsel + k), Bg[k]);   // deflate

        if (t < NN) {
            float* Xc = (kx == 0) ? Xx : (kx == 1) ? Xy : Xz;
            Xc[t] = ufi + xb[t * 3 + kx];                        // x0 = lowrank + noise
        }
        __syncthreads();
    }

    // ---------------- Gradient descent: 10 steps ----------------
    // dx_i = (0.4/M) * sum_j W_ij (D_ij - DX_ij)/DX_ij * (x_i - x_j)
    const float stepc = 0.4f * Minv;
    #pragma unroll 1
    for (int st = 0; st < 10; ++st) {
        float xix = Xx[i], xiy = Xy[i], xiz = Xz[i];
        float gx = 0.f, gy = 0.f, gz = 0.f;
        #pragma unroll
        for (int k = 0; k < 32; ++k) {
            int j = jb + k;
            float dx = xix - Xx[j];                         // wave-uniform broadcasts
            float dy = xiy - Xy[j];
            float dz = xiz - Xz[j];
            float d2 = fmaf(dx, dx, fmaf(dy, dy, fmaf(dz, dz, 0.01f)));
            float DX = sqrtf(d2);
            float rv = __builtin_amdgcn_rcpf(DX);
            float c  = fmaf(Dreg[k] * rv, Wreg[k], -Wreg[k]);    // W*(D/DX - 1)
            gx = fmaf(c, dx, gx);
            gy = fmaf(c, dy, gy);
            gz = fmaf(c, dz, gz);
        }
        scrx[t] = gx; scry[t] = gy; scrz[t] = gz;
        __syncthreads();
        if (t < NN) {
            float sx = (scrx[t] + scrx[t + 128]) + (scrx[t + 256] + scrx[t + 384]);
            float sy = (scry[t] + scry[t + 128]) + (scry[t + 256] + scry[t + 384]);
            float sz = (scrz[t] + scrz[t + 128]) + (scrz[t + 256] + scrz[t + 384]);
            float dxv = sx * stepc, dyv = sy * stepc, dzv = sz * stepc;
            float spd = sqrtf(fmaf(dxv, dxv, fmaf(dyv, dyv, fmaf(dzv, dzv, 0.001f))));
            float alpha = 0.1f + 4.9f * (float)(10 - st) * 0.1f;
            float scl = alpha * tanhf(spd / alpha) / spd;
            Xx[t] = fmaf(dxv, scl, Xx[t]);
            Xy[t] = fmaf(dyv, scl, Xy[t]);
            Xz[t] = fmaf(dzv, scl, Xz[t]);
        }
        __syncthreads();
    }

    // ---------------- Output: mask * distances(X), float4 stores ----------------
    float* ob = out + (size_t)b * 16384;
    #pragma unroll
    for (int k = 0; k < 8; ++k) {
        int e4 = t + k * 512;                  // float4 index
        int ii = e4 >> 5, jjb = (e4 & 31) * 4;
        float xix = Xx[ii], xiy = Xy[ii], xiz = Xz[ii];     // uniform broadcast
        float4 vx = *(const float4*)&Xx[jjb];
        float4 vy = *(const float4*)&Xy[jjb];
        float4 vz = *(const float4*)&Xz[jjb];
        unsigned mw = maskb[ii * 4 + (jjb >> 5)];
        float4 o;
        {
            float dx = xix - vx.x, dy = xiy - vy.x, dz = xiz - vz.x;
            float d2 = fmaf(dx, dx, fmaf(dy, dy, fmaf(dz, dz, 0.01f)));
            o.x = ((mw >> ((jjb + 0) & 31)) & 1) ? sqrtf(d2) : 0.f;
        }
        {
            float dx = xix - vx.y, dy = xiy - vy.y, dz = xiz - vz.y;
            float d2 = fmaf(dx, dx, fmaf(dy, dy, fmaf(dz, dz, 0.01f)));
            o.y = ((mw >> ((jjb + 1) & 31)) & 1) ? sqrtf(d2) : 0.f;
        }
        {
            float dx = xix - vx.z, dy = xiy - vy.z, dz = xiz - vz.z;
            float d2 = fmaf(dx, dx, fmaf(dy, dy, fmaf(dz, dz, 0.01f)));
            o.z = ((mw >> ((jjb + 2) & 31)) & 1) ? sqrtf(d2) : 0.f;
        }
        {
            float dx = xix - vx.w, dy = xiy - vy.w, dz = xiz - vz.w;
            float d2 = fmaf(dx, dx, fmaf(dy, dy, fmaf(dz, dz, 0.01f)));
            o.w = ((mw >> ((jjb + 3) & 31)) & 1) ? sqrtf(d2) : 0.f;
        }
        ((float4*)ob)[e4] = o;
    }
}

extern "C" void kernel_launch(void* const* d_in, const int* in_sizes, int n_in,
                              void* d_out, int out_size, void* d_ws, size_t ws_size,
                              hipStream_t stream) {
    const float* edge_pred = (const float*)d_in[0];
    const int*   adj       = (const int*)  d_in[1];
    const float* dinit     = (const float*)d_in[2];
    const float* u_init    = (const float*)d_in[3];
    const float* x_noise   = (const float*)d_in[4];
    float*       out       = (float*)d_out;

    ts_gcn_kernel<<<512, NTH, 0, stream>>>(edge_pred, adj, dinit, u_init, x_noise, out);
}

// Round 3
// 344.886 us; speedup vs baseline: 1.5114x; 1.5114x over previous
//
#include <hip/hip_runtime.h>
#include <hip/hip_fp16.h>
#include <math.h>

#define NN   128
#define PSTR 132          // pool stride (floats): 16B-aligned rows -> ds_read_b128, min bank cycles
#define NTH  512

__device__ __forceinline__ float sp_softplus(float x) { return log1pf(expf(x)); }
__device__ __forceinline__ float rdlane(float v, int l) {
    return __int_as_float(__builtin_amdgcn_readlane(__float_as_int(v), l));
}

// launch_bounds 2nd arg: hipcc observed to use CUDA semantics (min BLOCKS/CU).
// (512,4) gave VGPR=64 -> catastrophic scratch spill (round 2: WRITE_SIZE 200MB).
// (512,2): 2 blocks/CU = 16 waves/CU = 4 waves/SIMD -> 128-VGPR cap. State fits.
__global__ void __launch_bounds__(NTH, 2)
ts_gcn_kernel(const float* __restrict__ edge_pred,
              const int*   __restrict__ adj,
              const float* __restrict__ d_init,
              const float* __restrict__ u_init,
              const float* __restrict__ x_noise,
              float* __restrict__ out)
{
    __shared__ __align__(16) float pool[NN * PSTR];  // 67.6 KB, staging then aliases
    __shared__ unsigned maskb[512];                  // adj-mask bitmap (diag excluded)
    __shared__ int s_cntM, s_cntN0;

    // aliases into pool (live only after last staging read)
    float* scrA = pool;            // [512]
    float* scrB = pool + 512;      // [512]
    float* scrC = pool + 1024;     // [512]
    float* Xx   = pool + 1536;     // [128]
    float* Xy   = pool + 1664;     // [128]
    float* Xz   = pool + 1792;     // [128]
    float* r_s  = pool + 1920;     // [128]

    const int b    = blockIdx.x;
    const int t    = threadIdx.x;
    const int lane = t & 63;
    const int i    = t & 127;      // owned row
    const int q    = t >> 7;       // column quarter
    const int jb   = q * 32;
    const int lsel = jb & 63;
    const int hi6  = (t >> 6) & 1; // which 64-row half this thread's row is in

    const float dini = d_init[0];
    if (t == 0) { s_cntM = 0; s_cntN0 = 0; }

    // ---------------- Pass A: stage adj, build mask bitmap ----------------
    const int4* adj4 = (const int4*)(adj + (size_t)b * 16384);
    #pragma unroll
    for (int k = 0; k < 8; ++k) {
        int e4 = t + k * 512;
        int4 v = adj4[e4];
        int ii = e4 >> 5, jj = (e4 & 31) * 4;
        float* p = &pool[ii * PSTR + jj];
        p[0] = __int_as_float(v.x); p[1] = __int_as_float(v.y);
        p[2] = __int_as_float(v.z); p[3] = __int_as_float(v.w);
    }
    __syncthreads();
    unsigned mword = 0;
    #pragma unroll
    for (int k = 0; k < 32; ++k) {
        int j = jb + k;
        int a = __float_as_int(pool[i * PSTR + j]) | __float_as_int(pool[j * PSTR + i]);
        if (a != 0 && i != j) mword |= (1u << k);
    }
    maskb[i * 4 + q] = mword;
    int cm = __popc(mword);
    #pragma unroll
    for (int off = 32; off; off >>= 1) cm += __shfl_xor(cm, off);
    if (lane == 0) atomicAdd(&s_cntM, cm);
    if (i == 0)    atomicAdd(&s_cntN0, __popc(mword));  // row0 == col0 by symmetry
    __syncthreads();

    // ---------------- Pass B: stage ep.ch0 -> D (fp32 regs + packed half) ----------------
    const float4* ep4 = (const float4*)(edge_pred + (size_t)b * 32768);
    #pragma unroll
    for (int k = 0; k < 16; ++k) {
        int e2 = t + k * 512;
        float4 v = ep4[e2];
        int ii = e2 >> 6, jj = (e2 & 63) * 2;
        *(float2*)&pool[ii * PSTR + jj] = make_float2(v.x, v.z);
    }
    __syncthreads();
    float    Dfull[32];
    unsigned DWh[32];          // lo16 = D half, hi16 = W half -> 32 regs for both matrices
    #pragma unroll
    for (int k = 0; k < 32; ++k) {
        int j = jb + k;
        float s = pool[i * PSTR + j] + pool[j * PSTR + i];
        float d = ((mword >> k) & 1) ? sp_softplus(dini + s) : 0.f;
        Dfull[k] = d;
        DWh[k] = (unsigned)__half_as_ushort(__float2half_rn(d));
    }
    __syncthreads();

    // ---------------- Pass C: stage ep.ch1 -> W (packed half) ----------------
    #pragma unroll
    for (int k = 0; k < 16; ++k) {
        int e2 = t + k * 512;
        float4 v = ep4[e2];
        int ii = e2 >> 6, jj = (e2 & 63) * 2;
        *(float2*)&pool[ii * PSTR + jj] = make_float2(v.y, v.w);
    }
    __syncthreads();
    #pragma unroll
    for (int k = 0; k < 32; ++k) {
        int j = jb + k;
        float s = pool[i * PSTR + j] + pool[j * PSTR + i];
        float w = ((mword >> k) & 1) ? sp_softplus(dini + s) : 0.f;
        DWh[k] |= ((unsigned)__half_as_ushort(__float2half_rn(w))) << 16;
    }
    __syncthreads();   // pool staging dead; aliases live from here

    // ---------------- Row sums of D^2 + grand mean ----------------
    float rp = 0.f;
    #pragma unroll
    for (int k = 0; k < 32; ++k) rp = fmaf(Dfull[k], Dfull[k], rp);
    scrA[t] = rp;
    __syncthreads();
    if (t < NN)
        r_s[t] = (scrA[t] + scrA[t + 128]) + (scrA[t + 256] + scrA[t + 384]);
    __syncthreads();
    float mt = r_s[lane] + r_s[lane + 64];
    #pragma unroll
    for (int off = 32; off; off >>= 1) mt += __shfl_xor(mt, off);

    const float Nmol  = (float)(1 + s_cntN0);
    const float Minv  = 1.0f / (float)(128 + s_cntM);
    const float invN  = 1.0f / Nmol;
    const float cmean = mt * invN * invN;

    // ---------------- Gram matrix into registers ----------------
    const float ri = r_s[i];
    float Bg[32];
    #pragma unroll
    for (int k = 0; k < 32; ++k) {
        int j = jb + k;
        float dv = Dfull[k];
        float v  = -0.5f * (dv * dv - ri * invN - r_s[j] * invN + cmean);
        bool msk = ((mword >> k) & 1) || (i == j);
        Bg[k] = msk ? v : 0.f;
    }
    // Dfull dead here

    // ---------------- Power iteration: 3 ranks x 10 steps, 1 barrier/step ----------------
    // invariant: v_{s+1} = (A v_s) / max(||v_s||, 1e-3)  (scale commutes with A;
    // identical arithmetic to reference's normalize-then-matvec)
    const float* ub = u_init  + (size_t)b * 384;
    const float* xb = x_noise + (size_t)b * 384;

    #pragma unroll 1
    for (int kx = 0; kx < 3; ++kx) {
        float ulo = ub[lane * 3 + kx];          // v_0 rows lane / lane+64
        float uhi = ub[(lane + 64) * 3 + kx];
        float* rd = scrA; float* wr = scrB;
        #pragma unroll 1
        for (int s = 0; s < 10; ++s) {
            if (s) {
                ulo = (rd[lane]      + rd[lane + 128]) + (rd[lane + 256] + rd[lane + 384]);
                uhi = (rd[lane + 64] + rd[lane + 192]) + (rd[lane + 320] + rd[lane + 448]);
            }
            float n2 = fmaf(ulo, ulo, uhi * uhi);
            #pragma unroll
            for (int off = 32; off; off >>= 1) n2 += __shfl_xor(n2, off);
            float inv = 1.0f / fmaxf(sqrtf(n2), 0.001f);
            float usel = (q < 2) ? ulo : uhi;    // wave-uniform half select
            float a0 = 0.f, a1 = 0.f;
            #pragma unroll
            for (int k = 0; k < 16; ++k) {
                a0 = fmaf(Bg[k],      rdlane(usel, lsel + k),      a0);
                a1 = fmaf(Bg[k + 16], rdlane(usel, lsel + k + 16), a1);
            }
            wr[t] = (a0 + a1) * inv;             // partials of v_{s+1}
            __syncthreads();
            float* tmp = rd; rd = wr; wr = tmp;
        }
        // v_10 in rd (partials)
        float ulo2 = (rd[lane]      + rd[lane + 128]) + (rd[lane + 256] + rd[lane + 384]);
        float uhi2 = (rd[lane + 64] + rd[lane + 192]) + (rd[lane + 320] + rd[lane + 448]);
        float e2 = fmaf(ulo2, ulo2, uhi2 * uhi2);
        #pragma unroll
        for (int off = 32; off; off >>= 1) e2 += __shfl_xor(e2, off);
        float esc  = 1.0f / sqrtf(sqrtf(e2 + 0.01f));     // (eig_sq+0.01)^-0.25
        float ufi  = (hi6 ? uhi2 : ulo2) * esc;           // row i component
        float uscl = ((q < 2) ? ulo2 : uhi2) * esc;
        #pragma unroll
        for (int k = 0; k < 32; ++k)
            Bg[k] = fmaf(-ufi, rdlane(uscl, lsel + k), Bg[k]);   // deflate
        if (t < NN) {
            float* Xc = (kx == 0) ? Xx : (kx == 1) ? Xy : Xz;
            Xc[t] = ufi + xb[t * 3 + kx];                        // x0 = lowrank + noise
        }
        __syncthreads();   // protect wr-buffer + X before next rank / grad
    }

    // ---------------- Gradient descent: 10 steps ----------------
    // dx_i = (0.4/M) * sum_j W_ij (D_ij - DX_ij)/DX_ij * (x_i - x_j)
    const float stepc = 0.4f * Minv;
    #pragma unroll 1
    for (int st = 0; st < 10; ++st) {
        float xix = Xx[i], xiy = Xy[i], xiz = Xz[i];
        float gx = 0.f, gy = 0.f, gz = 0.f;
        #pragma unroll
        for (int k = 0; k < 32; ++k) {
            int j = jb + k;
            unsigned pw = DWh[k];
            float Dk = __half2float(__ushort_as_half((unsigned short)(pw & 0xffffu)));
            float Wk = __half2float(__ushort_as_half((unsigned short)(pw >> 16)));
            float dx = xix - Xx[j];                     // wave-uniform broadcasts
            float dy = xiy - Xy[j];
            float dz = xiz - Xz[j];
            float d2 = fmaf(dx, dx, fmaf(dy, dy, fmaf(dz, dz, 0.01f)));
            float DX = sqrtf(d2);
            float rv = __builtin_amdgcn_rcpf(DX);
            float c  = fmaf(Dk * rv, Wk, -Wk);          // W*(D/DX - 1); 0 when masked (W=0)
            gx = fmaf(c, dx, gx);
            gy = fmaf(c, dy, gy);
            gz = fmaf(c, dz, gz);
        }
        scrA[t] = gx; scrB[t] = gy; scrC[t] = gz;
        __syncthreads();
        if (t < NN) {
            float sx = (scrA[t] + scrA[t + 128]) + (scrA[t + 256] + scrA[t + 384]);
            float sy = (scrB[t] + scrB[t + 128]) + (scrB[t + 256] + scrB[t + 384]);
            float sz = (scrC[t] + scrC[t + 128]) + (scrC[t + 256] + scrC[t + 384]);
            float dxv = sx * stepc, dyv = sy * stepc, dzv = sz * stepc;
            float spd = sqrtf(fmaf(dxv, dxv, fmaf(dyv, dyv, fmaf(dzv, dzv, 0.001f))));
            float alpha = 0.1f + 4.9f * (float)(10 - st) * 0.1f;
            float scl = alpha * tanhf(spd / alpha) / spd;
            Xx[t] = fmaf(dxv, scl, Xx[t]);
            Xy[t] = fmaf(dyv, scl, Xy[t]);
            Xz[t] = fmaf(dzv, scl, Xz[t]);
        }
        __syncthreads();
    }

    // ---------------- Output: mask * distances(X), float4 stores ----------------
    float* ob = out + (size_t)b * 16384;
    #pragma unroll
    for (int k = 0; k < 8; ++k) {
        int e4 = t + k * 512;
        int ii = e4 >> 5, jjb = (e4 & 31) * 4;
        float xix = Xx[ii], xiy = Xy[ii], xiz = Xz[ii];
        float4 vx = *(const float4*)&Xx[jjb];
        float4 vy = *(const float4*)&Xy[jjb];
        float4 vz = *(const float4*)&Xz[jjb];
        unsigned mw = maskb[ii * 4 + (jjb >> 5)];
        float4 o;
        {
            float dx = xix - vx.x, dy = xiy - vy.x, dz = xiz - vz.x;
            float d2 = fmaf(dx, dx, fmaf(dy, dy, fmaf(dz, dz, 0.01f)));
            o.x = ((mw >> ((jjb + 0) & 31)) & 1) ? sqrtf(d2) : 0.f;
        }
        {
            float dx = xix - vx.y, dy = xiy - vy.y, dz = xiz - vz.y;
            float d2 = fmaf(dx, dx, fmaf(dy, dy, fmaf(dz, dz, 0.01f)));
            o.y = ((mw >> ((jjb + 1) & 31)) & 1) ? sqrtf(d2) : 0.f;
        }
        {
            float dx = xix - vx.z, dy = xiy - vy.z, dz = xiz - vz.z;
            float d2 = fmaf(dx, dx, fmaf(dy, dy, fmaf(dz, dz, 0.01f)));
            o.z = ((mw >> ((jjb + 2) & 31)) & 1) ? sqrtf(d2) : 0.f;
        }
        {
            float dx = xix - vx.w, dy = xiy - vy.w, dz = xiz - vz.w;
            float d2 = fmaf(dx, dx, fmaf(dy, dy, fmaf(dz, dz, 0.01f)));
            o.w = ((mw >> ((jjb + 3) & 31)) & 1) ? sqrtf(d2) : 0.f;
        }
        ((float4*)ob)[e4] = o;
    }
}

extern "C" void kernel_launch(void* const* d_in, const int* in_sizes, int n_in,
                              void* d_out, int out_size, void* d_ws, size_t ws_size,
                              hipStream_t stream) {
    const float* edge_pred = (const float*)d_in[0];
    const int*   adj       = (const int*)  d_in[1];
    const float* dinit     = (const float*)d_in[2];
    const float* u_init    = (const float*)d_in[3];
    const float* x_noise   = (const float*)d_in[4];
    float*       out       = (float*)d_out;

    ts_gcn_kernel<<<512, NTH, 0, stream>>>(edge_pred, adj, dinit, u_init, x_noise, out);
}

// Round 4
// 281.384 us; speedup vs baseline: 1.8525x; 1.2257x over previous
//
#include <hip/hip_runtime.h>
#include <hip/hip_fp16.h>
#include <math.h>

#define NN   128
#define PSTR 132          // pool stride (floats): 16B-aligned rows
#define NTH  512

// native-instruction softplus: max(x,0) + ln2 * log2(1 + 2^(-|x|*log2e))
// abs err ~1e-6 over x in [-20, 20]; trans ops only (v_exp_f32, v_log_f32)
__device__ __forceinline__ float sp_softplus(float x) {
    float p = __builtin_amdgcn_exp2f(fabsf(x) * -1.44269504f);
    float l = __builtin_amdgcn_logf(1.0f + p);
    return fmaxf(x, 0.0f) + 0.69314718f * l;
}
__device__ __forceinline__ float rdlane(float v, int l) {
    return __int_as_float(__builtin_amdgcn_readlane(__float_as_int(v), l));
}
__device__ __forceinline__ float rcpf(float x)  { return __builtin_amdgcn_rcpf(x); }
__device__ __forceinline__ float rsqf(float x)  { return __builtin_amdgcn_rsqf(x); }

// (512,2): 2 blocks/CU = 16 waves/CU = 4 waves/SIMD -> 128-VGPR cap.
// Round 3 landed exactly AT 128 and occupancy stayed 1 block/CU; this round the
// register peak is reduced (pass reorder) to land safely below the cliff.
__global__ void __launch_bounds__(NTH, 2)
ts_gcn_kernel(const float* __restrict__ edge_pred,
              const int*   __restrict__ adj,
              const float* __restrict__ d_init,
              const float* __restrict__ u_init,
              const float* __restrict__ x_noise,
              float* __restrict__ out)
{
    __shared__ __align__(16) float pool[NN * PSTR];  // 67.6 KB staging + aliases
    __shared__ unsigned maskb[512];
    __shared__ int s_cntM, s_cntN0;

    // aliases (live only after the covering staging pass is dead)
    float* scrA = pool;            // [512]
    float* scrB = pool + 512;      // [512]
    float* scrC = pool + 1024;     // [512]
    float* Xx   = pool + 1536;     // [128]
    float* Xy   = pool + 1664;     // [128]
    float* Xz   = pool + 1792;     // [128]
    float* r_s  = pool + 1920;     // [128]

    const int b    = blockIdx.x;
    const int t    = threadIdx.x;
    const int lane = t & 63;
    const int i    = t & 127;      // owned row
    const int q    = t >> 7;       // column quarter
    const int jb   = q * 32;
    const int lsel = jb & 63;
    const int hi6  = (t >> 6) & 1;

    const float dini = d_init[0];
    if (t == 0) { s_cntM = 0; s_cntN0 = 0; }

    // ---------------- Pass A: stage adj, build mask bitmap ----------------
    const int4* adj4 = (const int4*)(adj + (size_t)b * 16384);
    #pragma unroll 4
    for (int k = 0; k < 8; ++k) {
        int e4 = t + k * 512;
        int4 v = adj4[e4];
        int ii = e4 >> 5, jj = (e4 & 31) * 4;
        float* p = &pool[ii * PSTR + jj];
        p[0] = __int_as_float(v.x); p[1] = __int_as_float(v.y);
        p[2] = __int_as_float(v.z); p[3] = __int_as_float(v.w);
    }
    __syncthreads();
    unsigned mword = 0;
    #pragma unroll
    for (int k = 0; k < 32; ++k) {
        int j = jb + k;
        int a = __float_as_int(pool[i * PSTR + j]) | __float_as_int(pool[j * PSTR + i]);
        if (a != 0 && i != j) mword |= (1u << k);
    }
    maskb[i * 4 + q] = mword;
    int cm = __popc(mword);
    #pragma unroll
    for (int off = 32; off; off >>= 1) cm += __shfl_xor(cm, off);
    if (lane == 0) atomicAdd(&s_cntM, cm);
    if (i == 0)    atomicAdd(&s_cntN0, __popc(mword));
    __syncthreads();

    // ---------------- Pass B: stage ep.ch0 -> D ----------------
    const float4* ep4 = (const float4*)(edge_pred + (size_t)b * 32768);
    #pragma unroll 4
    for (int k = 0; k < 16; ++k) {
        int e2 = t + k * 512;
        float4 v = ep4[e2];
        int ii = e2 >> 6, jj = (e2 & 63) * 2;
        *(float2*)&pool[ii * PSTR + jj] = make_float2(v.x, v.z);
    }
    __syncthreads();
    float    Dfull[32];
    unsigned DWh[32];          // lo16 = D half, hi16 = W half
    #pragma unroll
    for (int k = 0; k < 32; ++k) {
        int j = jb + k;
        float s = pool[i * PSTR + j] + pool[j * PSTR + i];
        float d = ((mword >> k) & 1) ? sp_softplus(dini + s) : 0.f;
        Dfull[k] = d;
        DWh[k] = (unsigned)__half_as_ushort(__float2half_rn(d));
    }
    __syncthreads();           // pool(ep.x) dead -> scrA writable

    // ---------------- Row sums of D^2 + grand mean ----------------
    float rp = 0.f;
    #pragma unroll
    for (int k = 0; k < 32; ++k) rp = fmaf(Dfull[k], Dfull[k], rp);
    scrA[t] = rp;
    __syncthreads();
    if (t < NN)
        r_s[t] = (scrA[t] + scrA[t + 128]) + (scrA[t + 256] + scrA[t + 384]);
    __syncthreads();
    float mt = r_s[lane] + r_s[lane + 64];
    #pragma unroll
    for (int off = 32; off; off >>= 1) mt += __shfl_xor(mt, off);

    const float Nmol  = (float)(1 + s_cntN0);
    const float Minv  = 1.0f / (float)(128 + s_cntM);
    const float invN  = 1.0f / Nmol;
    const float cmean = mt * invN * invN;

    // ---------------- Gram matrix into registers (Dfull dies here) ----------------
    const float ri = r_s[i];
    float Bg[32];
    #pragma unroll
    for (int k = 0; k < 32; ++k) {
        int j = jb + k;
        float dv = Dfull[k];
        float v  = -0.5f * (dv * dv - ri * invN - r_s[j] * invN + cmean);
        bool msk = ((mword >> k) & 1) || (i == j);
        Bg[k] = msk ? v : 0.f;
    }
    __syncthreads();           // r_s reads done -> pool fully writable

    // ---------------- Pass C: stage ep.ch1 -> W ----------------
    #pragma unroll 4
    for (int k = 0; k < 16; ++k) {
        int e2 = t + k * 512;
        float4 v = ep4[e2];
        int ii = e2 >> 6, jj = (e2 & 63) * 2;
        *(float2*)&pool[ii * PSTR + jj] = make_float2(v.y, v.w);
    }
    __syncthreads();
    #pragma unroll
    for (int k = 0; k < 32; ++k) {
        int j = jb + k;
        float s = pool[i * PSTR + j] + pool[j * PSTR + i];
        float w = ((mword >> k) & 1) ? sp_softplus(dini + s) : 0.f;
        DWh[k] |= ((unsigned)__half_as_ushort(__float2half_rn(w))) << 16;
    }
    __syncthreads();           // staging dead; scr ping-pong live

    // ---------------- Power iteration: 3 ranks x 10 steps, 1 barrier/step ----------------
    const float* ub = u_init  + (size_t)b * 384;
    const float* xb = x_noise + (size_t)b * 384;

    #pragma unroll 1
    for (int kx = 0; kx < 3; ++kx) {
        float ulo = ub[lane * 3 + kx];
        float uhi = ub[(lane + 64) * 3 + kx];
        float* rd = scrA; float* wr = scrB;
        #pragma unroll 1
        for (int s = 0; s < 10; ++s) {
            if (s) {
                ulo = (rd[lane]      + rd[lane + 128]) + (rd[lane + 256] + rd[lane + 384]);
                uhi = (rd[lane + 64] + rd[lane + 192]) + (rd[lane + 320] + rd[lane + 448]);
            }
            float n2 = fmaf(ulo, ulo, uhi * uhi);
            #pragma unroll
            for (int off = 32; off; off >>= 1) n2 += __shfl_xor(n2, off);
            float inv = rcpf(fmaxf(sqrtf(n2), 0.001f));
            float usel = (q < 2) ? ulo : uhi;
            float a0 = 0.f, a1 = 0.f;
            #pragma unroll
            for (int k = 0; k < 16; ++k) {
                a0 = fmaf(Bg[k],      rdlane(usel, lsel + k),      a0);
                a1 = fmaf(Bg[k + 16], rdlane(usel, lsel + k + 16), a1);
            }
            wr[t] = (a0 + a1) * inv;
            __syncthreads();
            float* tmp = rd; rd = wr; wr = tmp;
        }
        float ulo2 = (rd[lane]      + rd[lane + 128]) + (rd[lane + 256] + rd[lane + 384]);
        float uhi2 = (rd[lane + 64] + rd[lane + 192]) + (rd[lane + 320] + rd[lane + 448]);
        float e2 = fmaf(ulo2, ulo2, uhi2 * uhi2);
        #pragma unroll
        for (int off = 32; off; off >>= 1) e2 += __shfl_xor(e2, off);
        float esc  = rsqf(sqrtf(e2 + 0.01f));            // (eig_sq+0.01)^-0.25
        float ufi  = (hi6 ? uhi2 : ulo2) * esc;
        float uscl = ((q < 2) ? ulo2 : uhi2) * esc;
        #pragma unroll
        for (int k = 0; k < 32; ++k)
            Bg[k] = fmaf(-ufi, rdlane(uscl, lsel + k), Bg[k]);
        if (t < NN) {
            float* Xc = (kx == 0) ? Xx : (kx == 1) ? Xy : Xz;
            Xc[t] = ufi + xb[t * 3 + kx];
        }
        __syncthreads();
    }

    // ---------------- Gradient descent: 10 steps ----------------
    const float stepc = 0.4f * Minv;
    #pragma unroll 1
    for (int st = 0; st < 10; ++st) {
        float xix = Xx[i], xiy = Xy[i], xiz = Xz[i];
        float gx = 0.f, gy = 0.f, gz = 0.f;
        #pragma unroll
        for (int g = 0; g < 8; ++g) {
            // wave-uniform float4 broadcasts: 3 ds_read_b128 per 4 columns
            float4 vx = *(const float4*)&Xx[jb + 4 * g];
            float4 vy = *(const float4*)&Xy[jb + 4 * g];
            float4 vz = *(const float4*)&Xz[jb + 4 * g];
            #pragma unroll
            for (int c = 0; c < 4; ++c) {
                int k = 4 * g + c;
                unsigned pw = DWh[k];
                float Dk = __half2float(__ushort_as_half((unsigned short)(pw & 0xffffu)));
                float Wk = __half2float(__ushort_as_half((unsigned short)(pw >> 16)));
                float jx = (c == 0) ? vx.x : (c == 1) ? vx.y : (c == 2) ? vx.z : vx.w;
                float jy = (c == 0) ? vy.x : (c == 1) ? vy.y : (c == 2) ? vy.z : vy.w;
                float jz = (c == 0) ? vz.x : (c == 1) ? vz.y : (c == 2) ? vz.z : vz.w;
                float dx = xix - jx, dy = xiy - jy, dz = xiz - jz;
                float d2 = fmaf(dx, dx, fmaf(dy, dy, fmaf(dz, dz, 0.01f)));
                float rv = rcpf(sqrtf(d2));
                float c2 = fmaf(Dk * rv, Wk, -Wk);       // W*(D/DX - 1)
                gx = fmaf(c2, dx, gx);
                gy = fmaf(c2, dy, gy);
                gz = fmaf(c2, dz, gz);
            }
        }
        scrA[t] = gx; scrB[t] = gy; scrC[t] = gz;
        __syncthreads();
        if (t < NN) {
            float sx = (scrA[t] + scrA[t + 128]) + (scrA[t + 256] + scrA[t + 384]);
            float sy = (scrB[t] + scrB[t + 128]) + (scrB[t + 256] + scrB[t + 384]);
            float sz = (scrC[t] + scrC[t + 128]) + (scrC[t + 256] + scrC[t + 384]);
            float dxv = sx * stepc, dyv = sy * stepc, dzv = sz * stepc;
            float spd = sqrtf(fmaf(dxv, dxv, fmaf(dyv, dyv, fmaf(dzv, dzv, 0.001f))));
            float alpha = 0.1f + 4.9f * (float)(10 - st) * 0.1f;
            // fast tanh: (e-1)/(e+1), e = exp(2z), z = spd/alpha clamped
            float z  = fminf(spd * rcpf(alpha), 20.0f);
            float e  = __builtin_amdgcn_exp2f(z * 2.88539008f);
            float th = (e - 1.0f) * rcpf(e + 1.0f);
            float scl = alpha * th * rcpf(spd);
            Xx[t] = fmaf(dxv, scl, Xx[t]);
            Xy[t] = fmaf(dyv, scl, Xy[t]);
            Xz[t] = fmaf(dzv, scl, Xz[t]);
        }
        __syncthreads();
    }

    // ---------------- Output: mask * distances(X), float4 stores ----------------
    float* ob = out + (size_t)b * 16384;
    #pragma unroll
    for (int k = 0; k < 8; ++k) {
        int e4 = t + k * 512;
        int ii = e4 >> 5, jjb = (e4 & 31) * 4;
        float xix = Xx[ii], xiy = Xy[ii], xiz = Xz[ii];
        float4 vx = *(const float4*)&Xx[jjb];
        float4 vy = *(const float4*)&Xy[jjb];
        float4 vz = *(const float4*)&Xz[jjb];
        unsigned mw = maskb[ii * 4 + (jjb >> 5)];
        float4 o;
        {
            float dx = xix - vx.x, dy = xiy - vy.x, dz = xiz - vz.x;
            float d2 = fmaf(dx, dx, fmaf(dy, dy, fmaf(dz, dz, 0.01f)));
            o.x = ((mw >> ((jjb + 0) & 31)) & 1) ? sqrtf(d2) : 0.f;
        }
        {
            float dx = xix - vx.y, dy = xiy - vy.y, dz = xiz - vz.y;
            float d2 = fmaf(dx, dx, fmaf(dy, dy, fmaf(dz, dz, 0.01f)));
            o.y = ((mw >> ((jjb + 1) & 31)) & 1) ? sqrtf(d2) : 0.f;
        }
        {
            float dx = xix - vx.z, dy = xiy - vy.z, dz = xiz - vz.z;
            float d2 = fmaf(dx, dx, fmaf(dy, dy, fmaf(dz, dz, 0.01f)));
            o.z = ((mw >> ((jjb + 2) & 31)) & 1) ? sqrtf(d2) : 0.f;
        }
        {
            float dx = xix - vx.w, dy = xiy - vy.w, dz = xiz - vz.w;
            float d2 = fmaf(dx, dx, fmaf(dy, dy, fmaf(dz, dz, 0.01f)));
            o.w = ((mw >> ((jjb + 3) & 31)) & 1) ? sqrtf(d2) : 0.f;
        }
        ((float4*)ob)[e4] = o;
    }
}

extern "C" void kernel_launch(void* const* d_in, const int* in_sizes, int n_in,
                              void* d_out, int out_size, void* d_ws, size_t ws_size,
                              hipStream_t stream) {
    const float* edge_pred = (const float*)d_in[0];
    const int*   adj       = (const int*)  d_in[1];
    const float* dinit     = (const float*)d_in[2];
    const float* u_init    = (const float*)d_in[3];
    const float* x_noise   = (const float*)d_in[4];
    float*       out       = (float*)d_out;

    ts_gcn_kernel<<<512, NTH, 0, stream>>>(edge_pred, adj, dinit, u_init, x_noise, out);
}